// Round 7
// baseline (8609.730 us; speedup 1.0000x reference)
//
#include <hip/hip_runtime.h>
#include <math.h>

#define NN   16384   // nodes
#define DD   512     // feature dim
#define KNN  16      // neighbors
#define MT   64      // rows per block
#define CT   128     // cols per tile
#define KT   32      // k-slab staged in LDS
#define SPLIT 2      // column split (grid = 2 blocks/CU)
#define COLS (NN / SPLIT)
#define SIM_LD 132   // sim row stride (16B-aligned, breaks pow2)

// ---- Pass 0: row norms, bit-exact replica of np.linalg.norm(axis=-1) -------
// numpy FLOAT_pairwise_sum, NPY_SIMD base case at wheel baseline SSE3.
// (verified bit-exact in R6 — DO NOT TOUCH)
__global__ __launch_bounds__(256) void norm_kernel(const float* __restrict__ feat,
                                                   float* __restrict__ nrm) {
#pragma clang fp contract(off)
    const int t   = threadIdx.x;
    const int row = blockIdx.x * 64 + (t >> 2);
    const int bid = t & 3;                      // which 128-elem block
    const float4* p4 = (const float4*)(feat + (size_t)row * DD + bid * 128);

    float r[4][4];                              // r[m][j]
    #pragma unroll
    for (int m = 0; m < 4; m++) {
        float4 q = p4[m];
        r[m][0] = q.x * q.x; r[m][1] = q.y * q.y;
        r[m][2] = q.z * q.z; r[m][3] = q.w * q.w;
    }
    #pragma unroll
    for (int tt = 1; tt < 8; tt++) {
        #pragma unroll
        for (int m = 0; m < 4; m++) {
            float4 q = p4[tt * 4 + m];
            r[m][0] += q.x * q.x; r[m][1] += q.y * q.y;
            r[m][2] += q.z * q.z; r[m][3] += q.w * q.w;
        }
    }
    float v0 = (r[0][0] + r[1][0]) + (r[2][0] + r[3][0]);
    float v1 = (r[0][1] + r[1][1]) + (r[2][1] + r[3][1]);
    float v2 = (r[0][2] + r[1][2]) + (r[2][2] + r[3][2]);
    float v3 = (r[0][3] + r[1][3]) + (r[2][3] + r[3][3]);
    float B  = (v0 + v1) + (v2 + v3);
    B += __shfl_xor(B, 1, 64);
    B += __shfl_xor(B, 2, 64);
    if (bid == 0) nrm[row] = sqrtf(B) + 1e-10f;
}

// ---- Pass 0b: fn = feature / nrm, IEEE-CR fp32 division --------------------
__global__ __launch_bounds__(256) void fn_kernel(const float* __restrict__ feat,
                                                 const float* __restrict__ nrm,
                                                 float* __restrict__ fn) {
    int i4  = blockIdx.x * 256 + threadIdx.x;
    int row = i4 >> 7;
    float n = nrm[row];
    float4 v = ((const float4*)feat)[i4];
    ((float4*)fn)[i4] = make_float4(v.x / n, v.y / n, v.z / n, v.w / n);
}

// ---- Pass 1: fused GEMM + per-split top-16.
// 128 threads/block; thread tile 8 rows x 8 cols (acc[8][8], 64 VGPRs).
// GEMM semantics IDENTICAL to R6: one accumulator per C element, single
// ascending-k FMA chain over all 512. blockIdx.y = column split.
template <bool PRE>
__global__ __launch_bounds__(128) void knn_kernel(const float* __restrict__ src,
                                                  const float* __restrict__ nrm,
                                                  float* __restrict__ pval,
                                                  int* __restrict__ pidx) {
    __shared__ union {
        struct { float As[KT][MT]; float Bs[KT][CT]; } stage;  // 24.0 KB
        float sim[MT][SIM_LD];                                 // 33.8 KB
    } u;
    __shared__ float tval[MT][KNN];  // sorted descending
    __shared__ int   tidx[MT][KNN];

    const int t  = threadIdx.x;          // 0..127
    const int r0 = blockIdx.x * MT;
    const int s  = blockIdx.y;           // column split id
    const int cb = s * COLS;             // split column base
    const int tx = t & 15;               // col group
    const int ty = t >> 4;               // row group: rows ty*8..+7

    for (int i = t; i < MT * KNN; i += 128) {
        ((float*)tval)[i] = -3.4e38f;
        ((int*)tidx)[i]   = 0;
    }

    // staging assignments (128 threads)
    const int arow = t >> 1, ah = t & 1;  // A: 64 rows x 2 k-halves (16 floats)
    const int bcol = t;                   // B: 128 cols x 32 k each

    for (int ct = 0; ct < COLS / CT; ct++) {
        const int c0 = cb + ct * CT;
        float acc[8][8];
        #pragma unroll
        for (int rr = 0; rr < 8; rr++)
            #pragma unroll
            for (int cc = 0; cc < 8; cc++) acc[rr][cc] = 0.0f;

        for (int kt = 0; kt < DD / KT; kt++) {
            const int kb = kt * KT;
            __syncthreads();  // previous users of union done (compute/merge)

            {   // stage A: 64x32 -> As[k][row], write bank = arow%32 (2-way, free)
                const float* ap = src + (size_t)(r0 + arow) * DD + kb + ah * 16;
                float4 a0 = *(const float4*)ap;
                float4 a1 = *(const float4*)(ap + 4);
                float4 a2 = *(const float4*)(ap + 8);
                float4 a3 = *(const float4*)(ap + 12);
                if (!PRE) {
                    float nA = nrm[r0 + arow];
                    a0.x /= nA; a0.y /= nA; a0.z /= nA; a0.w /= nA;
                    a1.x /= nA; a1.y /= nA; a1.z /= nA; a1.w /= nA;
                    a2.x /= nA; a2.y /= nA; a2.z /= nA; a2.w /= nA;
                    a3.x /= nA; a3.y /= nA; a3.z /= nA; a3.w /= nA;
                }
                int k0 = ah * 16;
                u.stage.As[k0 +  0][arow] = a0.x; u.stage.As[k0 +  1][arow] = a0.y;
                u.stage.As[k0 +  2][arow] = a0.z; u.stage.As[k0 +  3][arow] = a0.w;
                u.stage.As[k0 +  4][arow] = a1.x; u.stage.As[k0 +  5][arow] = a1.y;
                u.stage.As[k0 +  6][arow] = a1.z; u.stage.As[k0 +  7][arow] = a1.w;
                u.stage.As[k0 +  8][arow] = a2.x; u.stage.As[k0 +  9][arow] = a2.y;
                u.stage.As[k0 + 10][arow] = a2.z; u.stage.As[k0 + 11][arow] = a2.w;
                u.stage.As[k0 + 12][arow] = a3.x; u.stage.As[k0 + 13][arow] = a3.y;
                u.stage.As[k0 + 14][arow] = a3.z; u.stage.As[k0 + 15][arow] = a3.w;
            }
            {   // stage B: 128x32 -> Bs[k][col], write bank = bcol%32 (2-way, free)
                const float* bp = src + (size_t)(c0 + bcol) * DD + kb;
                float nB = PRE ? 1.0f : nrm[c0 + bcol];
                #pragma unroll
                for (int q = 0; q < 8; q++) {
                    float4 b = *(const float4*)(bp + q * 4);
                    if (!PRE) { b.x /= nB; b.y /= nB; b.z /= nB; b.w /= nB; }
                    u.stage.Bs[q * 4 + 0][bcol] = b.x;
                    u.stage.Bs[q * 4 + 1][bcol] = b.y;
                    u.stage.Bs[q * 4 + 2][bcol] = b.z;
                    u.stage.Bs[q * 4 + 3][bcol] = b.w;
                }
            }
            __syncthreads();

            // single ascending-k FMA chain, one accumulator per C element
            #pragma unroll
            for (int kk = 0; kk < KT; kk++) {
                float4 av0 = *(const float4*)&u.stage.As[kk][ty * 8];
                float4 av1 = *(const float4*)&u.stage.As[kk][ty * 8 + 4];
                float4 bv0 = *(const float4*)&u.stage.Bs[kk][tx * 4];
                float4 bv1 = *(const float4*)&u.stage.Bs[kk][64 + tx * 4];
                float ar[8] = {av0.x, av0.y, av0.z, av0.w,
                               av1.x, av1.y, av1.z, av1.w};
                float br[8] = {bv0.x, bv0.y, bv0.z, bv0.w,
                               bv1.x, bv1.y, bv1.z, bv1.w};
                #pragma unroll
                for (int rr = 0; rr < 8; rr++)
                    #pragma unroll
                    for (int cc = 0; cc < 8; cc++)
                        acc[rr][cc] = __builtin_fmaf(ar[rr], br[cc], acc[rr][cc]);
            }
        }
        __syncthreads();  // As/Bs reads done before sim overwrites union

        {   // park 64x128 sim tile
            #pragma unroll
            for (int rr = 0; rr < 8; rr++) {
                *(float4*)&u.sim[ty * 8 + rr][tx * 4] =
                    make_float4(acc[rr][0], acc[rr][1], acc[rr][2], acc[rr][3]);
                *(float4*)&u.sim[ty * 8 + rr][64 + tx * 4] =
                    make_float4(acc[rr][4], acc[rr][5], acc[rr][6], acc[rr][7]);
            }
        }
        __syncthreads();

        // streaming top-16 merge; 64 scanning threads (32 active lanes/wave).
        // strict '>' == jax.lax.top_k stable tie-break (lower index wins).
        if ((t & 1) == 0) {
            const int lr = t >> 1, grow = r0 + lr;
            float vmin = tval[lr][KNN - 1];
            for (int j = 0; j < CT / 4; j++) {
                float4 v4 = *(const float4*)&u.sim[lr][j * 4];
                float vs[4] = {v4.x, v4.y, v4.z, v4.w};
                #pragma unroll
                for (int e = 0; e < 4; e++) {
                    int c = c0 + j * 4 + e;
                    float v = vs[e];
                    if (c == grow) continue;   // zeroed diag never in top-16
                    if (v > vmin) {
                        int p = KNN - 1;
                        while (p > 0 && tval[lr][p - 1] < v) {
                            tval[lr][p] = tval[lr][p - 1];
                            tidx[lr][p] = tidx[lr][p - 1];
                            p--;
                        }
                        tval[lr][p] = v;
                        tidx[lr][p] = c;
                        vmin = tval[lr][KNN - 1];
                    }
                }
            }
        }
        // next iteration's first __syncthreads fences merge vs restage
    }

    __syncthreads();
    // emit per-split sorted candidate lists
    for (int i = t; i < MT * KNN; i += 128) {
        int lr = i / KNN, j = i % KNN;
        size_t o = ((size_t)s * NN + (r0 + lr)) * KNN + j;
        pval[o] = tval[lr][j];
        pidx[o] = tidx[lr][j];
    }
}

// ---- Pass 2: merge the SPLIT sorted top-16 lists per row -------------------
// split-0 indices are all < split-1 indices, so on equal values list 0 wins
// ('>=') — exactly jax.lax.top_k's stable lower-index-first tie-break.
__global__ __launch_bounds__(256) void merge_kernel(const float* __restrict__ pval,
                                                    const int* __restrict__ pidx,
                                                    int* __restrict__ out) {
    int row = blockIdx.x * 256 + threadIdx.x;
    if (row >= NN) return;
    const float* v0 = pval + (size_t)row * KNN;
    const float* v1 = pval + ((size_t)NN + row) * KNN;
    const int*   i0 = pidx + (size_t)row * KNN;
    const int*   i1 = pidx + ((size_t)NN + row) * KNN;
    int a = 0, b = 0;
    #pragma unroll
    for (int k = 0; k < KNN; k++) {
        // a+b = k <= 15, so a,b < 16: no OOB
        bool take0 = v0[a] >= v1[b];
        int idx = take0 ? i0[a] : i1[b];
        if (take0) a++; else b++;
        out[(size_t)row * KNN + k]            = row;
        out[(size_t)NN * KNN + row * KNN + k] = idx;
    }
}

extern "C" void kernel_launch(void* const* d_in, const int* in_sizes, int n_in,
                              void* d_out, int out_size, void* d_ws, size_t ws_size,
                              hipStream_t stream) {
    const float* feat = (const float*)d_in[0];
    char* ws = (char*)d_ws;
    float* pval = (float*)ws;                                  // 2 MB
    int*   pidx = (int*)(ws + (size_t)SPLIT * NN * KNN * 4);   // 2 MB
    float* nrm  = (float*)(ws + 2 * (size_t)SPLIT * NN * KNN * 4);  // 64 KB
    float* fn   = (float*)((char*)nrm + NN * 4);               // 32 MB
    int*   out  = (int*)d_out;                                 // int32

    norm_kernel<<<NN / 64, 256, 0, stream>>>(feat, nrm);

    const size_t need = 2 * (size_t)SPLIT * NN * KNN * 4 + NN * 4
                      + (size_t)NN * DD * sizeof(float);
    dim3 kgrid(NN / MT, SPLIT);
    if (ws_size >= need) {
        fn_kernel<<<(NN * DD / 4) / 256, 256, 0, stream>>>(feat, nrm, fn);
        knn_kernel<true><<<kgrid, 128, 0, stream>>>(fn, nrm, pval, pidx);
    } else {
        // divide during staging (bitwise-identical IEEE div, just redundant)
        knn_kernel<false><<<kgrid, 128, 0, stream>>>(feat, nrm, pval, pidx);
    }
    merge_kernel<<<NN / 256, 256, 0, stream>>>(pval, pidx, out);
}

// Round 8
// 1232.866 us; speedup vs baseline: 6.9835x; 6.9835x over previous
//
#include <hip/hip_runtime.h>
#include <math.h>

#define NN   16384
#define DD   512
#define KNN  16
#define CAND 48          // candidates kept per row (recall margin ~2.6e-2 >> bf16 err)
#define STRIPW 2048      // sim strip width (128 MB fp32, fits LLC)
#define NSTRIP (NN / STRIPW)
#define LDT  56          // LDS bf16 row pitch: 112B = 16B-aligned, 2-way banks only

typedef __attribute__((ext_vector_type(8))) short bf16x8;
typedef __attribute__((ext_vector_type(4))) float f32x4;

// ---- Pass 0: row norms, bit-exact replica of np.linalg.norm (R6-verified) --
__global__ __launch_bounds__(256) void norm_kernel(const float* __restrict__ feat,
                                                   float* __restrict__ nrm) {
#pragma clang fp contract(off)
    const int t   = threadIdx.x;
    const int row = blockIdx.x * 64 + (t >> 2);
    const int bid = t & 3;
    const float4* p4 = (const float4*)(feat + (size_t)row * DD + bid * 128);
    float r[4][4];
    #pragma unroll
    for (int m = 0; m < 4; m++) {
        float4 q = p4[m];
        r[m][0] = q.x * q.x; r[m][1] = q.y * q.y;
        r[m][2] = q.z * q.z; r[m][3] = q.w * q.w;
    }
    #pragma unroll
    for (int tt = 1; tt < 8; tt++) {
        #pragma unroll
        for (int m = 0; m < 4; m++) {
            float4 q = p4[tt * 4 + m];
            r[m][0] += q.x * q.x; r[m][1] += q.y * q.y;
            r[m][2] += q.z * q.z; r[m][3] += q.w * q.w;
        }
    }
    float v0 = (r[0][0] + r[1][0]) + (r[2][0] + r[3][0]);
    float v1 = (r[0][1] + r[1][1]) + (r[2][1] + r[3][1]);
    float v2 = (r[0][2] + r[1][2]) + (r[2][2] + r[3][2]);
    float v3 = (r[0][3] + r[1][3]) + (r[2][3] + r[3][3]);
    float B  = (v0 + v1) + (v2 + v3);
    B += __shfl_xor(B, 1, 64);
    B += __shfl_xor(B, 2, 64);
    if (bid == 0) nrm[row] = sqrtf(B) + 1e-10f;
}

// ---- Pass 0b: fn = feature/nrm (IEEE-CR, R6-verified) + bf16 copy ----------
__device__ inline ushort bf16rne(float f) {
    unsigned u = __float_as_uint(f);
    u += 0x7fffu + ((u >> 16) & 1u);
    return (ushort)(u >> 16);
}
__global__ __launch_bounds__(256) void fn_kernel(const float* __restrict__ feat,
                                                 const float* __restrict__ nrm,
                                                 float* __restrict__ fn,
                                                 ushort* __restrict__ fnb) {
    int i4  = blockIdx.x * 256 + threadIdx.x;
    int row = i4 >> 7;
    float n = nrm[row];
    float4 v = ((const float4*)feat)[i4];
    float4 o = make_float4(v.x / n, v.y / n, v.z / n, v.w / n);
    ((float4*)fn)[i4] = o;
    ushort4 b = {bf16rne(o.x), bf16rne(o.y), bf16rne(o.z), bf16rne(o.w)};
    ((ushort4*)fnb)[i4] = b;
}

// ---- Pass 1a: bf16 MFMA GEMM -> fp32 sim strip -----------------------------
// 256 threads = 4 waves (2x2), block tile 128x128, wave tile 64x64 = 4x4
// frags of 16x16x32. A/B frag: lane&15 = matrix row/col, (lane>>4)*8+j = k
// (any consistent k-permutation cancels between A and B). C/D: col=lane&15,
// row=(lane>>4)*4+reg [m89-verified].
__global__ __launch_bounds__(256) void gemm_kernel(const ushort* __restrict__ fnb,
                                                   int stripBase,
                                                   float* __restrict__ simS) {
    __shared__ ushort As[128][LDT];
    __shared__ ushort Bs[128][LDT];
    const int t    = threadIdx.x;
    const int wave = t >> 6, lane = t & 63;
    const int rbase = blockIdx.y * 128;            // global row base
    const int cbL   = blockIdx.x * 128;            // strip-local col base
    const int wr = (wave >> 1) * 64, wc = (wave & 1) * 64;
    const int m = lane & 15, quad = lane >> 4;
    const int srow = t >> 1, sh = (t & 1) * 16;    // staging: 128 rows x 2 halves

    f32x4 acc[4][4];
    #pragma unroll
    for (int i = 0; i < 4; i++)
        #pragma unroll
        for (int j = 0; j < 4; j++) acc[i][j] = (f32x4){0.f, 0.f, 0.f, 0.f};

    for (int kb = 0; kb < DD; kb += 32) {
        __syncthreads();
        {   // stage A rows, B cols (both from fnb, 16 bf16 per thread each)
            const ushort* ap = fnb + (size_t)(rbase + srow) * DD + kb + sh;
            const ushort* bp = fnb + (size_t)(stripBase + cbL + srow) * DD + kb + sh;
            *(int4*)&As[srow][sh]     = *(const int4*)(ap);
            *(int4*)&As[srow][sh + 8] = *(const int4*)(ap + 8);
            *(int4*)&Bs[srow][sh]     = *(const int4*)(bp);
            *(int4*)&Bs[srow][sh + 8] = *(const int4*)(bp + 8);
        }
        __syncthreads();
        bf16x8 af[4], bfr[4];
        #pragma unroll
        for (int i = 0; i < 4; i++) {
            af[i]  = *(const bf16x8*)&As[wr + i * 16 + m][quad * 8];
            bfr[i] = *(const bf16x8*)&Bs[wc + i * 16 + m][quad * 8];
        }
        #pragma unroll
        for (int i = 0; i < 4; i++)
            #pragma unroll
            for (int j = 0; j < 4; j++)
                acc[i][j] = __builtin_amdgcn_mfma_f32_16x16x32_bf16(
                    af[i], bfr[j], acc[i][j], 0, 0, 0);
    }
    #pragma unroll
    for (int i = 0; i < 4; i++)
        #pragma unroll
        for (int j = 0; j < 4; j++)
            #pragma unroll
            for (int r = 0; r < 4; r++) {
                int grow = rbase + wr + i * 16 + quad * 4 + r;
                int gcol = cbL + wc + j * 16 + m;
                simS[(size_t)grow * STRIPW + gcol] = acc[i][j][r];
            }
}

// ---- Pass 1b: update per-row top-CAND from a sim strip ---------------------
// One wave per row; sorted-descending (v, idx-asc) list lives in lanes
// 0..CAND-1 registers; ballot-admit + wave-parallel O(1) insert.
__global__ __launch_bounds__(256) void select_kernel(const float* __restrict__ simS,
                                                     int stripBase, int firstStrip,
                                                     float* __restrict__ lval,
                                                     int* __restrict__ lidx) {
    const int lane = threadIdx.x & 63;
    const int row  = blockIdx.x * 4 + (threadIdx.x >> 6);
    float lv; int li;
    if (firstStrip) { lv = -3.4e38f; li = 0x7fffffff; }
    else {
        lv = (lane < CAND) ? lval[(size_t)row * CAND + lane] : -3.4e38f;
        li = (lane < CAND) ? lidx[(size_t)row * CAND + lane] : 0x7fffffff;
    }
    const float* sp = simS + (size_t)row * STRIPW;
    for (int it = 0; it < STRIPW / 64; it++) {
        int   c = stripBase + it * 64 + lane;
        float v = sp[it * 64 + lane];
        float vmin = __shfl(lv, CAND - 1);
        int   imin = __shfl(li, CAND - 1);
        bool adm = ((v > vmin) || (v == vmin && c < imin)) && (c != row);
        unsigned long long mask = __ballot(adm);
        while (mask) {
            int src = __builtin_ctzll(mask); mask &= mask - 1;
            float bv = __shfl(v, src);
            int   bc = stripBase + it * 64 + src;
            // rank among current list (strict lexicographic better)
            bool better = (lv > bv) || (lv == bv && li < bc);
            unsigned long long bb = __ballot(better) & ((1ull << CAND) - 1);
            int p = __popcll(bb);
            if (p < CAND) {
                float pv = __shfl_up(lv, 1);
                int   pi = __shfl_up(li, 1);
                float nlv = (lane < p) ? lv : (lane == p ? bv : pv);
                int   nli = (lane < p) ? li : (lane == p ? bc : pi);
                if (lane < CAND) { lv = nlv; li = nli; }
            }
        }
    }
    if (lane < CAND) {
        lval[(size_t)row * CAND + lane] = lv;
        lidx[(size_t)row * CAND + lane] = li;
    }
}

// ---- Pass 2: exact fp32-chain rescore of CAND candidates, emit top-16 ------
// Replicates the reference sim bitwise: single ascending-k fmaf chain on fn.
__global__ __launch_bounds__(256) void rescore_kernel(const float* __restrict__ fn,
                                                      const int* __restrict__ lidx,
                                                      int* __restrict__ out) {
    __shared__ float sv[4][64];
    __shared__ int   si[4][64];
    const int w = threadIdx.x >> 6, lane = threadIdx.x & 63;
    const int row = blockIdx.x * 4 + w;
    const bool valid = lane < CAND;
    const int c = valid ? lidx[(size_t)row * CAND + lane] : 0;
    const float* q = fn + (size_t)row * DD;
    const float* p = fn + (size_t)c * DD;
    float s = 0.0f;
    for (int k = 0; k < DD; k++) s = __builtin_fmaf(q[k], p[k], s);
    sv[w][lane] = valid ? s : -3.4e38f;
    si[w][lane] = valid ? c : 0x7fffffff;
    __syncthreads();
    if (valid) {
        int rank = 0;
        #pragma unroll 8
        for (int mm = 0; mm < CAND; mm++) {
            float vm = sv[w][mm];
            rank += (vm > s) || (vm == s && si[w][mm] < c);
        }
        if (rank < KNN) {
            out[(size_t)row * KNN + rank]            = row;
            out[(size_t)NN * KNN + row * KNN + rank] = c;
        }
    }
}

// ================= R6 exact fused kernel (ws fallback; verified) ============
#define MT 64
#define CT 128
#define KT 32
#define SIM_LD 132
template <bool PRE>
__global__ __launch_bounds__(256) void knn_exact_kernel(const float* __restrict__ src,
                                                        const float* __restrict__ nrm,
                                                        int* __restrict__ out) {
    __shared__ union {
        struct { float As[KT][MT]; float Bs[KT][CT]; } stage;
        float sim[MT][SIM_LD];
    } u;
    __shared__ float tval[MT][KNN];
    __shared__ int   tidx[MT][KNN];
    const int t  = threadIdx.x;
    const int r0 = blockIdx.x * MT;
    const int tx = t & 15;
    const int ty = t >> 4;
    for (int i = t; i < MT * KNN; i += 256) {
        ((float*)tval)[i] = -3.4e38f;
        ((int*)tidx)[i]   = 0;
    }
    const int arow = t >> 2, akq = t & 3;
    const int bcol = t >> 1, bkh = t & 1;
    for (int ct = 0; ct < NN / CT; ct++) {
        const int c0 = ct * CT;
        float acc[4][8];
        #pragma unroll
        for (int rr = 0; rr < 4; rr++)
            #pragma unroll
            for (int cc = 0; cc < 8; cc++) acc[rr][cc] = 0.0f;
        for (int kt = 0; kt < DD / KT; kt++) {
            const int kb = kt * KT;
            __syncthreads();
            {
                const float* ap = src + (size_t)(r0 + arow) * DD + kb + akq * 8;
                float4 a0 = *(const float4*)ap;
                float4 a1 = *(const float4*)(ap + 4);
                if (!PRE) {
                    float nA = nrm[r0 + arow];
                    a0.x /= nA; a0.y /= nA; a0.z /= nA; a0.w /= nA;
                    a1.x /= nA; a1.y /= nA; a1.z /= nA; a1.w /= nA;
                }
                int k0 = akq * 8;
                u.stage.As[k0 + 0][arow] = a0.x; u.stage.As[k0 + 1][arow] = a0.y;
                u.stage.As[k0 + 2][arow] = a0.z; u.stage.As[k0 + 3][arow] = a0.w;
                u.stage.As[k0 + 4][arow] = a1.x; u.stage.As[k0 + 5][arow] = a1.y;
                u.stage.As[k0 + 6][arow] = a1.z; u.stage.As[k0 + 7][arow] = a1.w;
            }
            {
                const float* bp = src + (size_t)(c0 + bcol) * DD + kb + bkh * 16;
                float4 b0 = *(const float4*)bp;
                float4 b1 = *(const float4*)(bp + 4);
                float4 b2 = *(const float4*)(bp + 8);
                float4 b3 = *(const float4*)(bp + 12);
                if (!PRE) {
                    float nB = nrm[c0 + bcol];
                    b0.x /= nB; b0.y /= nB; b0.z /= nB; b0.w /= nB;
                    b1.x /= nB; b1.y /= nB; b1.z /= nB; b1.w /= nB;
                    b2.x /= nB; b2.y /= nB; b2.z /= nB; b2.w /= nB;
                    b3.x /= nB; b3.y /= nB; b3.z /= nB; b3.w /= nB;
                }
                int k0 = bkh * 16;
                u.stage.Bs[k0 +  0][bcol] = b0.x; u.stage.Bs[k0 +  1][bcol] = b0.y;
                u.stage.Bs[k0 +  2][bcol] = b0.z; u.stage.Bs[k0 +  3][bcol] = b0.w;
                u.stage.Bs[k0 +  4][bcol] = b1.x; u.stage.Bs[k0 +  5][bcol] = b1.y;
                u.stage.Bs[k0 +  6][bcol] = b1.z; u.stage.Bs[k0 +  7][bcol] = b1.w;
                u.stage.Bs[k0 +  8][bcol] = b2.x; u.stage.Bs[k0 +  9][bcol] = b2.y;
                u.stage.Bs[k0 + 10][bcol] = b2.z; u.stage.Bs[k0 + 11][bcol] = b2.w;
                u.stage.Bs[k0 + 12][bcol] = b3.x; u.stage.Bs[k0 + 13][bcol] = b3.y;
                u.stage.Bs[k0 + 14][bcol] = b3.z; u.stage.Bs[k0 + 15][bcol] = b3.w;
            }
            __syncthreads();
            #pragma unroll
            for (int kk = 0; kk < KT; kk++) {
                float4 av  = *(const float4*)&u.stage.As[kk][ty * 4];
                float4 bv0 = *(const float4*)&u.stage.Bs[kk][tx * 4];
                float4 bv1 = *(const float4*)&u.stage.Bs[kk][64 + tx * 4];
                float ar[4] = {av.x, av.y, av.z, av.w};
                float br[8] = {bv0.x, bv0.y, bv0.z, bv0.w,
                               bv1.x, bv1.y, bv1.z, bv1.w};
                #pragma unroll
                for (int rr = 0; rr < 4; rr++)
                    #pragma unroll
                    for (int cc = 0; cc < 8; cc++)
                        acc[rr][cc] = __builtin_fmaf(ar[rr], br[cc], acc[rr][cc]);
            }
        }
        __syncthreads();
        {
            #pragma unroll
            for (int rr = 0; rr < 4; rr++) {
                *(float4*)&u.sim[ty * 4 + rr][tx * 4] =
                    make_float4(acc[rr][0], acc[rr][1], acc[rr][2], acc[rr][3]);
                *(float4*)&u.sim[ty * 4 + rr][64 + tx * 4] =
                    make_float4(acc[rr][4], acc[rr][5], acc[rr][6], acc[rr][7]);
            }
        }
        __syncthreads();
        if ((t & 3) == 0) {
            const int lr = t >> 2, grow = r0 + lr;
            float vmin = tval[lr][KNN - 1];
            for (int j = 0; j < CT / 4; j++) {
                float4 v4 = *(const float4*)&u.sim[lr][j * 4];
                float vs[4] = {v4.x, v4.y, v4.z, v4.w};
                #pragma unroll
                for (int e = 0; e < 4; e++) {
                    int cc2 = c0 + j * 4 + e;
                    float v = vs[e];
                    if (cc2 == grow) continue;
                    if (v > vmin) {
                        int p = KNN - 1;
                        while (p > 0 && tval[lr][p - 1] < v) {
                            tval[lr][p] = tval[lr][p - 1];
                            tidx[lr][p] = tidx[lr][p - 1];
                            p--;
                        }
                        tval[lr][p] = v;
                        tidx[lr][p] = cc2;
                        vmin = tval[lr][KNN - 1];
                    }
                }
            }
        }
    }
    __syncthreads();
    for (int i = t; i < MT * KNN; i += 256) {
        int lr = i / KNN, j = i % KNN;
        int grow = r0 + lr;
        out[(size_t)grow * KNN + j]            = grow;
        out[(size_t)NN * KNN + grow * KNN + j] = tidx[lr][j];
    }
}

extern "C" void kernel_launch(void* const* d_in, const int* in_sizes, int n_in,
                              void* d_out, int out_size, void* d_ws, size_t ws_size,
                              hipStream_t stream) {
    const float* feat = (const float*)d_in[0];
    int* out = (int*)d_out;
    char* ws = (char*)d_ws;

    // ws layout
    const size_t oNrm  = 0;
    const size_t oFn   = 64 * 1024;
    const size_t oFnb  = oFn  + (size_t)NN * DD * 4;        // +32 MB
    const size_t oLv   = oFnb + (size_t)NN * DD * 2;        // +16 MB
    const size_t oLi   = oLv  + (size_t)NN * CAND * 4;      // +3 MB
    const size_t oSim  = oLi  + (size_t)NN * CAND * 4;      // +3 MB
    const size_t need  = oSim + (size_t)NN * STRIPW * 4;    // +128 MB
    float*  nrm  = (float*)(ws + oNrm);
    float*  fn   = (float*)(ws + oFn);
    ushort* fnb  = (ushort*)(ws + oFnb);
    float*  lval = (float*)(ws + oLv);
    int*    lidx = (int*)(ws + oLi);
    float*  simS = (float*)(ws + oSim);

    norm_kernel<<<NN / 64, 256, 0, stream>>>(feat, nrm);

    if (ws_size >= need) {
        fn_kernel<<<(NN * DD / 4) / 256, 256, 0, stream>>>(feat, nrm, fn, fnb);
        for (int s = 0; s < NSTRIP; s++) {
            dim3 ggrid(STRIPW / 128, NN / 128);
            gemm_kernel<<<ggrid, 256, 0, stream>>>(fnb, s * STRIPW, simS);
            select_kernel<<<NN / 4, 256, 0, stream>>>(simS, s * STRIPW, s == 0,
                                                      lval, lidx);
        }
        rescore_kernel<<<NN / 4, 256, 0, stream>>>(fn, lidx, out);
    } else if (ws_size >= oFn + (size_t)NN * DD * 4) {
        // fallback: R6 exact fused path with prenormalized fn (fp32 only)
        fn_kernel<<<(NN * DD / 4) / 256, 256, 0, stream>>>(feat, nrm, fn,
                                                           (ushort*)(ws + oFn));
        // NOTE: fnb overlaps nothing used by exact path; reuse fn buffer only
        knn_exact_kernel<true><<<NN / MT, 256, 0, stream>>>(fn, nrm, out);
    } else {
        knn_exact_kernel<false><<<NN / MT, 256, 0, stream>>>(feat, nrm, out);
    }
}

// Round 9
// 1005.458 us; speedup vs baseline: 8.5630x; 1.2262x over previous
//
#include <hip/hip_runtime.h>
#include <hip/hip_fp16.h>
#include <math.h>

#define NN   16384
#define DD   512
#define KNN  16
#define CAND 32          // candidates/row (margin rank16->32 ~1.3e-2 >> 4e-4 err)
#define STRIPW 4096      // fp16 sim strip: 16384 x 4096 x 2B = 128 MB
#define NSTRIP (NN / STRIPW)
#define KT2  64          // k-chunk per barrier-pair
#define LDK  72          // LDS bf16 row pitch (144 B): 16B-aligned, optimal 8-phase banks

typedef __attribute__((ext_vector_type(8))) short bf16x8;
typedef __attribute__((ext_vector_type(4))) float f32x4;

// ---- Pass 0: row norms, bit-exact replica of np.linalg.norm (R6-verified) --
__global__ __launch_bounds__(256) void norm_kernel(const float* __restrict__ feat,
                                                   float* __restrict__ nrm) {
#pragma clang fp contract(off)
    const int t   = threadIdx.x;
    const int row = blockIdx.x * 64 + (t >> 2);
    const int bid = t & 3;
    const float4* p4 = (const float4*)(feat + (size_t)row * DD + bid * 128);
    float r[4][4];
    #pragma unroll
    for (int m = 0; m < 4; m++) {
        float4 q = p4[m];
        r[m][0] = q.x * q.x; r[m][1] = q.y * q.y;
        r[m][2] = q.z * q.z; r[m][3] = q.w * q.w;
    }
    #pragma unroll
    for (int tt = 1; tt < 8; tt++) {
        #pragma unroll
        for (int m = 0; m < 4; m++) {
            float4 q = p4[tt * 4 + m];
            r[m][0] += q.x * q.x; r[m][1] += q.y * q.y;
            r[m][2] += q.z * q.z; r[m][3] += q.w * q.w;
        }
    }
    float v0 = (r[0][0] + r[1][0]) + (r[2][0] + r[3][0]);
    float v1 = (r[0][1] + r[1][1]) + (r[2][1] + r[3][1]);
    float v2 = (r[0][2] + r[1][2]) + (r[2][2] + r[3][2]);
    float v3 = (r[0][3] + r[1][3]) + (r[2][3] + r[3][3]);
    float B  = (v0 + v1) + (v2 + v3);
    B += __shfl_xor(B, 1, 64);
    B += __shfl_xor(B, 2, 64);
    if (bid == 0) nrm[row] = sqrtf(B) + 1e-10f;
}

// ---- Pass 0b: fn = feature/nrm (IEEE-CR, R6-verified) + bf16 copy ----------
__device__ inline ushort bf16rne(float f) {
    unsigned u = __float_as_uint(f);
    u += 0x7fffu + ((u >> 16) & 1u);
    return (ushort)(u >> 16);
}
__global__ __launch_bounds__(256) void fn_kernel(const float* __restrict__ feat,
                                                 const float* __restrict__ nrm,
                                                 float* __restrict__ fn,
                                                 ushort* __restrict__ fnb) {
    int i4  = blockIdx.x * 256 + threadIdx.x;
    int row = i4 >> 7;
    float n = nrm[row];
    float4 v = ((const float4*)feat)[i4];
    float4 o = make_float4(v.x / n, v.y / n, v.z / n, v.w / n);
    ((float4*)fn)[i4] = o;
    ushort4 b = {bf16rne(o.x), bf16rne(o.y), bf16rne(o.z), bf16rne(o.w)};
    ((ushort4*)fnb)[i4] = b;
}

// ---- Pass 1a: bf16 MFMA GEMM -> fp16 sim strip -----------------------------
// 256 thr = 4 waves (2x2 of 64x64), block tile 128x128, KT2=64 per barrier
// pair (32 MFMA/wave between barriers). LDS pitch 144B: staging b128 stores
// and frag b128 reads both hit the optimal 8-phase bank schedule.
// C/D mapping (m89-verified): col=lane&15, row=(lane>>4)*4+reg.
__global__ __launch_bounds__(256) void gemm_kernel(const ushort* __restrict__ fnb,
                                                   int stripBase,
                                                   __half* __restrict__ simS) {
    __shared__ ushort As[128][LDK];
    __shared__ ushort Bs[128][LDK];
    const int t    = threadIdx.x;
    const int wave = t >> 6, lane = t & 63;
    const int rbase = blockIdx.y * 128;
    const int cbL   = blockIdx.x * 128;            // strip-local col base
    const int wr = (wave >> 1) * 64, wc = (wave & 1) * 64;
    const int m = lane & 15, quad = lane >> 4;
    const int srow = t >> 1, shalf = (t & 1) * 32; // staging: 128 rows x 2 halves

    f32x4 acc[4][4];
    #pragma unroll
    for (int i = 0; i < 4; i++)
        #pragma unroll
        for (int j = 0; j < 4; j++) acc[i][j] = (f32x4){0.f, 0.f, 0.f, 0.f};

    const ushort* arow = fnb + (size_t)(rbase + srow) * DD + shalf;
    const ushort* brow = fnb + (size_t)(stripBase + cbL + srow) * DD + shalf;

    for (int kb = 0; kb < DD; kb += KT2) {
        __syncthreads();  // protect previous chunk's frag reads
        #pragma unroll
        for (int j = 0; j < 4; j++) {
            *(int4*)&As[srow][shalf + j * 8] = *(const int4*)(arow + kb + j * 8);
            *(int4*)&Bs[srow][shalf + j * 8] = *(const int4*)(brow + kb + j * 8);
        }
        __syncthreads();

        #pragma unroll
        for (int ks = 0; ks < KT2; ks += 32) {
            bf16x8 af[4], bv[4];
            #pragma unroll
            for (int i = 0; i < 4; i++)
                af[i] = *(const bf16x8*)&As[wr + i * 16 + m][ks + quad * 8];
            #pragma unroll
            for (int j = 0; j < 4; j++)
                bv[j] = *(const bf16x8*)&Bs[wc + j * 16 + m][ks + quad * 8];
            #pragma unroll
            for (int i = 0; i < 4; i++)
                #pragma unroll
                for (int j = 0; j < 4; j++)
                    acc[i][j] = __builtin_amdgcn_mfma_f32_16x16x32_bf16(
                        af[i], bv[j], acc[i][j], 0, 0, 0);
        }
    }
    #pragma unroll
    for (int i = 0; i < 4; i++)
        #pragma unroll
        for (int j = 0; j < 4; j++)
            #pragma unroll
            for (int r = 0; r < 4; r++) {
                int grow = rbase + wr + i * 16 + quad * 4 + r;
                int gcol = cbL + wc + j * 16 + m;
                simS[(size_t)grow * STRIPW + gcol] = __float2half(acc[i][j][r]);
            }
}

// ---- Pass 1b: update per-row top-CAND from an fp16 sim strip ---------------
// One wave per row; sorted (v desc, idx asc) list in lanes 0..31; ballot
// admit + wave-parallel insert. (structure R8-verified)
__global__ __launch_bounds__(256) void select_kernel(const __half* __restrict__ simS,
                                                     int stripBase, int firstStrip,
                                                     float* __restrict__ lval,
                                                     int* __restrict__ lidx) {
    const int lane = threadIdx.x & 63;
    const int row  = blockIdx.x * 4 + (threadIdx.x >> 6);
    float lv; int li;
    if (firstStrip) { lv = -3.4e38f; li = 0x7fffffff; }
    else {
        lv = (lane < CAND) ? lval[(size_t)row * CAND + lane] : -3.4e38f;
        li = (lane < CAND) ? lidx[(size_t)row * CAND + lane] : 0x7fffffff;
    }
    const __half* sp = simS + (size_t)row * STRIPW;
    for (int it = 0; it < STRIPW / 64; it++) {
        int   c = stripBase + it * 64 + lane;
        float v = __half2float(sp[it * 64 + lane]);
        float vmin = __shfl(lv, CAND - 1);
        int   imin = __shfl(li, CAND - 1);
        bool adm = ((v > vmin) || (v == vmin && c < imin)) && (c != row);
        unsigned long long mask = __ballot(adm);
        while (mask) {
            int src = __builtin_ctzll(mask); mask &= mask - 1;
            float bvv = __shfl(v, src);
            int   bc  = stripBase + it * 64 + src;
            bool better = (lv > bvv) || (lv == bvv && li < bc);
            unsigned long long bb = __ballot(better) & ((1ull << CAND) - 1);
            int p = __popcll(bb);
            if (p < CAND) {
                float pv = __shfl_up(lv, 1);
                int   pi = __shfl_up(li, 1);
                float nlv = (lane < p) ? lv : (lane == p ? bvv : pv);
                int   nli = (lane < p) ? li : (lane == p ? bc : pi);
                if (lane < CAND) { lv = nlv; li = nli; }
            }
        }
    }
    if (lane < CAND) {
        lval[(size_t)row * CAND + lane] = lv;
        lidx[(size_t)row * CAND + lane] = li;
    }
}

// ---- Pass 2: exact fp32-chain rescore of CAND candidates, emit top-16 ------
// Bitwise-replicates the reference sim: single ascending-k fmaf chain on fn.
// 2 rows per wave (half-wave = one row's 32 candidates), no idle lanes.
__global__ __launch_bounds__(256) void rescore_kernel(const float* __restrict__ fn,
                                                      const int* __restrict__ lidx,
                                                      int* __restrict__ out) {
    __shared__ float sv[8][CAND];
    __shared__ int   si[8][CAND];
    const int w    = threadIdx.x >> 5;        // half-wave 0..7
    const int lane = threadIdx.x & 31;
    const int row  = blockIdx.x * 8 + w;
    const int c = lidx[(size_t)row * CAND + lane];
    const float* q = fn + (size_t)row * DD;
    const float* p = fn + (size_t)c * DD;
    float s = 0.0f;
    for (int k = 0; k < DD; k += 4) {
        float4 qv = *(const float4*)(q + k);
        float4 pv = *(const float4*)(p + k);
        s = __builtin_fmaf(qv.x, pv.x, s);
        s = __builtin_fmaf(qv.y, pv.y, s);
        s = __builtin_fmaf(qv.z, pv.z, s);
        s = __builtin_fmaf(qv.w, pv.w, s);
    }
    sv[w][lane] = s;
    si[w][lane] = c;
    __syncthreads();
    int rank = 0;
    #pragma unroll 8
    for (int mm = 0; mm < CAND; mm++) {
        float vm = sv[w][mm];
        rank += (vm > s) || (vm == s && si[w][mm] < c);
    }
    if (rank < KNN) {
        out[(size_t)row * KNN + rank]            = row;
        out[(size_t)NN * KNN + row * KNN + rank] = c;
    }
}

// ================= R6 exact fused kernel (ws fallback; verified) ============
#define MT 64
#define CT 128
#define KT 32
#define SIM_LD 132
template <bool PRE>
__global__ __launch_bounds__(256) void knn_exact_kernel(const float* __restrict__ src,
                                                        const float* __restrict__ nrm,
                                                        int* __restrict__ out) {
    __shared__ union {
        struct { float As[KT][MT]; float Bs[KT][CT]; } stage;
        float sim[MT][SIM_LD];
    } u;
    __shared__ float tval[MT][KNN];
    __shared__ int   tidx[MT][KNN];
    const int t  = threadIdx.x;
    const int r0 = blockIdx.x * MT;
    const int tx = t & 15;
    const int ty = t >> 4;
    for (int i = t; i < MT * KNN; i += 256) {
        ((float*)tval)[i] = -3.4e38f;
        ((int*)tidx)[i]   = 0;
    }
    const int arow = t >> 2, akq = t & 3;
    const int bcol = t >> 1, bkh = t & 1;
    for (int ct = 0; ct < NN / CT; ct++) {
        const int c0 = ct * CT;
        float acc[4][8];
        #pragma unroll
        for (int rr = 0; rr < 4; rr++)
            #pragma unroll
            for (int cc = 0; cc < 8; cc++) acc[rr][cc] = 0.0f;
        for (int kt = 0; kt < DD / KT; kt++) {
            const int kb = kt * KT;
            __syncthreads();
            {
                const float* ap = src + (size_t)(r0 + arow) * DD + kb + akq * 8;
                float4 a0 = *(const float4*)ap;
                float4 a1 = *(const float4*)(ap + 4);
                if (!PRE) {
                    float nA = nrm[r0 + arow];
                    a0.x /= nA; a0.y /= nA; a0.z /= nA; a0.w /= nA;
                    a1.x /= nA; a1.y /= nA; a1.z /= nA; a1.w /= nA;
                }
                int k0 = akq * 8;
                u.stage.As[k0 + 0][arow] = a0.x; u.stage.As[k0 + 1][arow] = a0.y;
                u.stage.As[k0 + 2][arow] = a0.z; u.stage.As[k0 + 3][arow] = a0.w;
                u.stage.As[k0 + 4][arow] = a1.x; u.stage.As[k0 + 5][arow] = a1.y;
                u.stage.As[k0 + 6][arow] = a1.z; u.stage.As[k0 + 7][arow] = a1.w;
            }
            {
                const float* bp = src + (size_t)(c0 + bcol) * DD + kb + bkh * 16;
                float4 b0 = *(const float4*)bp;
                float4 b1 = *(const float4*)(bp + 4);
                float4 b2 = *(const float4*)(bp + 8);
                float4 b3 = *(const float4*)(bp + 12);
                if (!PRE) {
                    float nB = nrm[c0 + bcol];
                    b0.x /= nB; b0.y /= nB; b0.z /= nB; b0.w /= nB;
                    b1.x /= nB; b1.y /= nB; b1.z /= nB; b1.w /= nB;
                    b2.x /= nB; b2.y /= nB; b2.z /= nB; b2.w /= nB;
                    b3.x /= nB; b3.y /= nB; b3.z /= nB; b3.w /= nB;
                }
                int k0 = bkh * 16;
                u.stage.Bs[k0 +  0][bcol] = b0.x; u.stage.Bs[k0 +  1][bcol] = b0.y;
                u.stage.Bs[k0 +  2][bcol] = b0.z; u.stage.Bs[k0 +  3][bcol] = b0.w;
                u.stage.Bs[k0 +  4][bcol] = b1.x; u.stage.Bs[k0 +  5][bcol] = b1.y;
                u.stage.Bs[k0 +  6][bcol] = b1.z; u.stage.Bs[k0 +  7][bcol] = b1.w;
                u.stage.Bs[k0 +  8][bcol] = b2.x; u.stage.Bs[k0 +  9][bcol] = b2.y;
                u.stage.Bs[k0 + 10][bcol] = b2.z; u.stage.Bs[k0 + 11][bcol] = b2.w;
                u.stage.Bs[k0 + 12][bcol] = b3.x; u.stage.Bs[k0 + 13][bcol] = b3.y;
                u.stage.Bs[k0 + 14][bcol] = b3.z; u.stage.Bs[k0 + 15][bcol] = b3.w;
            }
            __syncthreads();
            #pragma unroll
            for (int kk = 0; kk < KT; kk++) {
                float4 av  = *(const float4*)&u.stage.As[kk][ty * 4];
                float4 bv0 = *(const float4*)&u.stage.Bs[kk][tx * 4];
                float4 bv1 = *(const float4*)&u.stage.Bs[kk][64 + tx * 4];
                float ar[4] = {av.x, av.y, av.z, av.w};
                float br[8] = {bv0.x, bv0.y, bv0.z, bv0.w,
                               bv1.x, bv1.y, bv1.z, bv1.w};
                #pragma unroll
                for (int rr = 0; rr < 4; rr++)
                    #pragma unroll
                    for (int cc = 0; cc < 8; cc++)
                        acc[rr][cc] = __builtin_fmaf(ar[rr], br[cc], acc[rr][cc]);
            }
        }
        __syncthreads();
        {
            #pragma unroll
            for (int rr = 0; rr < 4; rr++) {
                *(float4*)&u.sim[ty * 4 + rr][tx * 4] =
                    make_float4(acc[rr][0], acc[rr][1], acc[rr][2], acc[rr][3]);
                *(float4*)&u.sim[ty * 4 + rr][64 + tx * 4] =
                    make_float4(acc[rr][4], acc[rr][5], acc[rr][6], acc[rr][7]);
            }
        }
        __syncthreads();
        if ((t & 3) == 0) {
            const int lr = t >> 2, grow = r0 + lr;
            float vmin = tval[lr][KNN - 1];
            for (int j = 0; j < CT / 4; j++) {
                float4 v4 = *(const float4*)&u.sim[lr][j * 4];
                float vs[4] = {v4.x, v4.y, v4.z, v4.w};
                #pragma unroll
                for (int e = 0; e < 4; e++) {
                    int cc2 = c0 + j * 4 + e;
                    float v = vs[e];
                    if (cc2 == grow) continue;
                    if (v > vmin) {
                        int p = KNN - 1;
                        while (p > 0 && tval[lr][p - 1] < v) {
                            tval[lr][p] = tval[lr][p - 1];
                            tidx[lr][p] = tidx[lr][p - 1];
                            p--;
                        }
                        tval[lr][p] = v;
                        tidx[lr][p] = cc2;
                        vmin = tval[lr][KNN - 1];
                    }
                }
            }
        }
    }
    __syncthreads();
    for (int i = t; i < MT * KNN; i += 256) {
        int lr = i / KNN, j = i % KNN;
        int grow = r0 + lr;
        out[(size_t)grow * KNN + j]            = grow;
        out[(size_t)NN * KNN + grow * KNN + j] = tidx[lr][j];
    }
}

extern "C" void kernel_launch(void* const* d_in, const int* in_sizes, int n_in,
                              void* d_out, int out_size, void* d_ws, size_t ws_size,
                              hipStream_t stream) {
    const float* feat = (const float*)d_in[0];
    int* out = (int*)d_out;
    char* ws = (char*)d_ws;

    const size_t oNrm  = 0;
    const size_t oFn   = 64 * 1024;
    const size_t oFnb  = oFn  + (size_t)NN * DD * 4;        // +32 MB
    const size_t oLv   = oFnb + (size_t)NN * DD * 2;        // +16 MB
    const size_t oLi   = oLv  + (size_t)NN * CAND * 4;      // +2 MB
    const size_t oSim  = oLi  + (size_t)NN * CAND * 4;      // +2 MB
    const size_t need  = oSim + (size_t)NN * STRIPW * 2;    // +128 MB
    float*  nrm  = (float*)(ws + oNrm);
    float*  fn   = (float*)(ws + oFn);
    ushort* fnb  = (ushort*)(ws + oFnb);
    float*  lval = (float*)(ws + oLv);
    int*    lidx = (int*)(ws + oLi);
    __half* simS = (__half*)(ws + oSim);

    norm_kernel<<<NN / 64, 256, 0, stream>>>(feat, nrm);

    if (ws_size >= need) {
        fn_kernel<<<(NN * DD / 4) / 256, 256, 0, stream>>>(feat, nrm, fn, fnb);
        for (int s = 0; s < NSTRIP; s++) {
            dim3 ggrid(STRIPW / 128, NN / 128);
            gemm_kernel<<<ggrid, 256, 0, stream>>>(fnb, s * STRIPW, simS);
            select_kernel<<<NN / 4, 256, 0, stream>>>(simS, s * STRIPW, s == 0,
                                                      lval, lidx);
        }
        rescore_kernel<<<NN / 8, 256, 0, stream>>>(fn, lidx, out);
    } else if (ws_size >= oFn + (size_t)NN * DD * 4) {
        fn_kernel<<<(NN * DD / 4) / 256, 256, 0, stream>>>(feat, nrm, fn,
                                                           (ushort*)(ws + oFn));
        knn_exact_kernel<true><<<NN / MT, 256, 0, stream>>>(fn, nrm, out);
    } else {
        knn_exact_kernel<false><<<NN / MT, 256, 0, stream>>>(feat, nrm, out);
    }
}

// Round 10
// 881.039 us; speedup vs baseline: 9.7723x; 1.1412x over previous
//
#include <hip/hip_runtime.h>
#include <hip/hip_fp16.h>
#include <math.h>

#define NN   16384
#define DD   512
#define KNN  16
#define CAND 24          // candidates/row (margin rank16->24 ~6.6e-3 >> 3e-4 err)
#define STRIPW 4096      // fp16 sim strip: 16384 x 4096 x 2B = 128 MB (fits LLC)
#define NSTRIP (NN / STRIPW)

typedef __attribute__((ext_vector_type(8))) short bf16x8;
typedef __attribute__((ext_vector_type(4))) float f32x4;
typedef unsigned int u32;

// async global->LDS, 16B per lane; dest = wave-uniform base + lane*16
__device__ __forceinline__ void load16_lds(const ushort* g, void* l) {
    __builtin_amdgcn_global_load_lds(
        (const __attribute__((address_space(1))) u32*)(const void*)g,
        (__attribute__((address_space(3))) u32*)l, 16, 0, 0);
}

// ---- Pass 0: row norms, bit-exact replica of np.linalg.norm (R6-verified) --
__global__ __launch_bounds__(256) void norm_kernel(const float* __restrict__ feat,
                                                   float* __restrict__ nrm) {
#pragma clang fp contract(off)
    const int t   = threadIdx.x;
    const int row = blockIdx.x * 64 + (t >> 2);
    const int bid = t & 3;
    const float4* p4 = (const float4*)(feat + (size_t)row * DD + bid * 128);
    float r[4][4];
    #pragma unroll
    for (int m = 0; m < 4; m++) {
        float4 q = p4[m];
        r[m][0] = q.x * q.x; r[m][1] = q.y * q.y;
        r[m][2] = q.z * q.z; r[m][3] = q.w * q.w;
    }
    #pragma unroll
    for (int tt = 1; tt < 8; tt++) {
        #pragma unroll
        for (int m = 0; m < 4; m++) {
            float4 q = p4[tt * 4 + m];
            r[m][0] += q.x * q.x; r[m][1] += q.y * q.y;
            r[m][2] += q.z * q.z; r[m][3] += q.w * q.w;
        }
    }
    float v0 = (r[0][0] + r[1][0]) + (r[2][0] + r[3][0]);
    float v1 = (r[0][1] + r[1][1]) + (r[2][1] + r[3][1]);
    float v2 = (r[0][2] + r[1][2]) + (r[2][2] + r[3][2]);
    float v3 = (r[0][3] + r[1][3]) + (r[2][3] + r[3][3]);
    float B  = (v0 + v1) + (v2 + v3);
    B += __shfl_xor(B, 1, 64);
    B += __shfl_xor(B, 2, 64);
    if (bid == 0) nrm[row] = sqrtf(B) + 1e-10f;
}

// ---- Pass 0b: fn = feature/nrm (IEEE-CR, R6-verified) + bf16 copy ----------
__device__ inline ushort bf16rne(float f) {
    unsigned u = __float_as_uint(f);
    u += 0x7fffu + ((u >> 16) & 1u);
    return (ushort)(u >> 16);
}
__global__ __launch_bounds__(256) void fn_kernel(const float* __restrict__ feat,
                                                 const float* __restrict__ nrm,
                                                 float* __restrict__ fn,
                                                 ushort* __restrict__ fnb) {
    int i4  = blockIdx.x * 256 + threadIdx.x;
    int row = i4 >> 7;
    float n = nrm[row];
    float4 v = ((const float4*)feat)[i4];
    float4 o = make_float4(v.x / n, v.y / n, v.z / n, v.w / n);
    ((float4*)fn)[i4] = o;
    ushort4 b = {bf16rne(o.x), bf16rne(o.y), bf16rne(o.z), bf16rne(o.w)};
    ((ushort4*)fnb)[i4] = b;
}

// ---- Pass 1a: bf16 MFMA GEMM -> fp16 sim strip (m97-style async staging) ---
// 256 thr = 4 waves (2x2 of 64x64), block tile 128x128, k-chunk 64.
// LDS layout: [row][64k] pad-free (1KB segments for global_load_lds), with
// 16B-chunk XOR swizzle (chunk ^ row&7) applied on the GLOBAL fetch address
// so ds_read_b128 frag reads are 2-way max (free).
__global__ __launch_bounds__(256) void gemm_kernel(const ushort* __restrict__ fnb,
                                                   int stripBase,
                                                   __half* __restrict__ simS) {
    __shared__ ushort As[128 * 64];   // 16 KB
    __shared__ ushort Bs[128 * 64];   // 16 KB
    const int t    = threadIdx.x;
    const int wave = t >> 6, lane = t & 63;
    const int rbase = blockIdx.y * 128;
    const int cbL   = blockIdx.x * 128;
    const int wr = (wave >> 1) * 64, wc = (wave & 1) * 64;
    const int m = lane & 15, quad = lane >> 4;
    const int rseg = lane >> 3;             // row within 8-row segment
    const int cchk = (lane & 7) ^ rseg;     // swizzled global 16B-chunk index

    f32x4 acc[4][4];
    #pragma unroll
    for (int i = 0; i < 4; i++)
        #pragma unroll
        for (int j = 0; j < 4; j++) acc[i][j] = (f32x4){0.f, 0.f, 0.f, 0.f};

    const int swz = ((m & 7) << 4);         // reader-side xor key (bytes)

    for (int kb = 0; kb < DD; kb += 64) {
        __syncthreads();                    // prev chunk frag reads done
        #pragma unroll
        for (int q = 0; q < 4; q++) {
            int s   = wave * 4 + q;         // segment 0..15 (8 rows each)
            int row = s * 8 + rseg;
            const ushort* ga = fnb + (size_t)(rbase + row) * DD + kb + cchk * 8;
            const ushort* gb = fnb + (size_t)(stripBase + cbL + row) * DD + kb + cchk * 8;
            load16_lds(ga, (char*)As + s * 1024);
            load16_lds(gb, (char*)Bs + s * 1024);
        }
        __syncthreads();                    // drains vmcnt (compiler-enforced)

        #pragma unroll
        for (int ks = 0; ks < 64; ks += 32) {
            const int cb16 = (ks >> 3) + quad;          // global 16B-chunk id
            const int off  = ((cb16 << 4) ^ swz);       // swizzled byte offset
            bf16x8 af[4], bv[4];
            #pragma unroll
            for (int i = 0; i < 4; i++)
                af[i] = *(const bf16x8*)((const char*)As + (wr + i * 16 + m) * 128 + off);
            #pragma unroll
            for (int j = 0; j < 4; j++)
                bv[j] = *(const bf16x8*)((const char*)Bs + (wc + j * 16 + m) * 128 + off);
            #pragma unroll
            for (int i = 0; i < 4; i++)
                #pragma unroll
                for (int j = 0; j < 4; j++)
                    acc[i][j] = __builtin_amdgcn_mfma_f32_16x16x32_bf16(
                        af[i], bv[j], acc[i][j], 0, 0, 0);
        }
    }
    // C/D mapping (m89-verified): col=lane&15, row=(lane>>4)*4+reg
    #pragma unroll
    for (int i = 0; i < 4; i++)
        #pragma unroll
        for (int j = 0; j < 4; j++)
            #pragma unroll
            for (int r = 0; r < 4; r++) {
                int grow = rbase + wr + i * 16 + quad * 4 + r;
                int gcol = cbL + wc + j * 16 + m;
                simS[(size_t)grow * STRIPW + gcol] = __float2half(acc[i][j][r]);
            }
}

// ---- Pass 1b: update per-row top-CAND from an fp16 sim strip (half2) -------
// One wave per row; sorted (v desc, idx asc) list in lanes 0..CAND-1.
__global__ __launch_bounds__(256) void select_kernel(const __half2* __restrict__ simS2,
                                                     int stripBase, int firstStrip,
                                                     float* __restrict__ lval,
                                                     int* __restrict__ lidx) {
    const int lane = threadIdx.x & 63;
    const int row  = blockIdx.x * 4 + (threadIdx.x >> 6);
    float lv; int li;
    if (firstStrip) { lv = -3.4e38f; li = 0x7fffffff; }
    else {
        lv = (lane < CAND) ? lval[(size_t)row * CAND + lane] : -3.4e38f;
        li = (lane < CAND) ? lidx[(size_t)row * CAND + lane] : 0x7fffffff;
    }
    const __half2* sp = simS2 + (size_t)row * (STRIPW / 2);
    for (int it = 0; it < STRIPW / 128; it++) {
        __half2 h = sp[it * 64 + lane];
        float v0 = __low2float(h), v1 = __high2float(h);
        int c0 = stripBase + it * 128 + lane * 2, c1 = c0 + 1;
        float vmin = __shfl(lv, CAND - 1);
        int   imin = __shfl(li, CAND - 1);
        bool a0 = ((v0 > vmin) || (v0 == vmin && c0 < imin)) && (c0 != row);
        bool a1 = ((v1 > vmin) || (v1 == vmin && c1 < imin)) && (c1 != row);
        unsigned long long m0 = __ballot(a0), m1 = __ballot(a1);
        #pragma unroll
        for (int ph = 0; ph < 2; ph++) {
            unsigned long long mask = ph ? m1 : m0;
            float vv = ph ? v1 : v0;
            while (mask) {
                int src = __builtin_ctzll(mask); mask &= mask - 1;
                float bvv = __shfl(vv, src);
                int   bc  = stripBase + it * 128 + src * 2 + ph;
                bool better = (lv > bvv) || (lv == bvv && li < bc);
                unsigned long long bb = __ballot(better) & ((1ull << CAND) - 1);
                int p = __popcll(bb);
                if (p < CAND) {
                    float pv = __shfl_up(lv, 1);
                    int   pi = __shfl_up(li, 1);
                    float nlv = (lane < p) ? lv : (lane == p ? bvv : pv);
                    int   nli = (lane < p) ? li : (lane == p ? bc : pi);
                    if (lane < CAND) { lv = nlv; li = nli; }
                }
            }
        }
    }
    if (lane < CAND) {
        lval[(size_t)row * CAND + lane] = lv;
        lidx[(size_t)row * CAND + lane] = li;
    }
}

// ---- Pass 2: exact fp32-chain rescore, emit top-16 -------------------------
// Bitwise-replicates the reference sim: single ascending-k fmaf chain on fn.
__global__ __launch_bounds__(256) void rescore_kernel(const float* __restrict__ fn,
                                                      const int* __restrict__ lidx,
                                                      int* __restrict__ out) {
    __shared__ float sv[8][CAND];
    __shared__ int   si[8][CAND];
    const int w    = threadIdx.x >> 5;        // 32-lane group 0..7
    const int lane = threadIdx.x & 31;
    const int row  = blockIdx.x * 8 + w;
    const bool valid = lane < CAND;
    const int c = valid ? lidx[(size_t)row * CAND + lane] : 0;
    const float* q = fn + (size_t)row * DD;
    const float* p = fn + (size_t)c * DD;
    float s = 0.0f;
    for (int k = 0; k < DD; k += 16) {   // wide loads for MLP; chain order exact
        float4 q0 = *(const float4*)(q + k),      p0 = *(const float4*)(p + k);
        float4 q1 = *(const float4*)(q + k + 4),  p1 = *(const float4*)(p + k + 4);
        float4 q2 = *(const float4*)(q + k + 8),  p2 = *(const float4*)(p + k + 8);
        float4 q3 = *(const float4*)(q + k + 12), p3 = *(const float4*)(p + k + 12);
        s = __builtin_fmaf(q0.x, p0.x, s); s = __builtin_fmaf(q0.y, p0.y, s);
        s = __builtin_fmaf(q0.z, p0.z, s); s = __builtin_fmaf(q0.w, p0.w, s);
        s = __builtin_fmaf(q1.x, p1.x, s); s = __builtin_fmaf(q1.y, p1.y, s);
        s = __builtin_fmaf(q1.z, p1.z, s); s = __builtin_fmaf(q1.w, p1.w, s);
        s = __builtin_fmaf(q2.x, p2.x, s); s = __builtin_fmaf(q2.y, p2.y, s);
        s = __builtin_fmaf(q2.z, p2.z, s); s = __builtin_fmaf(q2.w, p2.w, s);
        s = __builtin_fmaf(q3.x, p3.x, s); s = __builtin_fmaf(q3.y, p3.y, s);
        s = __builtin_fmaf(q3.z, p3.z, s); s = __builtin_fmaf(q3.w, p3.w, s);
    }
    if (valid) { sv[w][lane] = s; si[w][lane] = c; }
    __syncthreads();
    if (valid) {
        int rank = 0;
        #pragma unroll 8
        for (int mm = 0; mm < CAND; mm++) {
            float vm = sv[w][mm];
            rank += (vm > s) || (vm == s && si[w][mm] < c);
        }
        if (rank < KNN) {
            out[(size_t)row * KNN + rank]            = row;
            out[(size_t)NN * KNN + row * KNN + rank] = c;
        }
    }
}

// ================= R6 exact fused kernel (ws fallback; verified) ============
#define MT 64
#define CT 128
#define KT 32
#define SIM_LD 132
template <bool PRE>
__global__ __launch_bounds__(256) void knn_exact_kernel(const float* __restrict__ src,
                                                        const float* __restrict__ nrm,
                                                        int* __restrict__ out) {
    __shared__ union {
        struct { float As[KT][MT]; float Bs[KT][CT]; } stage;
        float sim[MT][SIM_LD];
    } u;
    __shared__ float tval[MT][KNN];
    __shared__ int   tidx[MT][KNN];
    const int t  = threadIdx.x;
    const int r0 = blockIdx.x * MT;
    const int tx = t & 15;
    const int ty = t >> 4;
    for (int i = t; i < MT * KNN; i += 256) {
        ((float*)tval)[i] = -3.4e38f;
        ((int*)tidx)[i]   = 0;
    }
    const int arow = t >> 2, akq = t & 3;
    const int bcol = t >> 1, bkh = t & 1;
    for (int ct = 0; ct < NN / CT; ct++) {
        const int c0 = ct * CT;
        float acc[4][8];
        #pragma unroll
        for (int rr = 0; rr < 4; rr++)
            #pragma unroll
            for (int cc = 0; cc < 8; cc++) acc[rr][cc] = 0.0f;
        for (int kt = 0; kt < DD / KT; kt++) {
            const int kb = kt * KT;
            __syncthreads();
            {
                const float* ap = src + (size_t)(r0 + arow) * DD + kb + akq * 8;
                float4 a0 = *(const float4*)ap;
                float4 a1 = *(const float4*)(ap + 4);
                if (!PRE) {
                    float nA = nrm[r0 + arow];
                    a0.x /= nA; a0.y /= nA; a0.z /= nA; a0.w /= nA;
                    a1.x /= nA; a1.y /= nA; a1.z /= nA; a1.w /= nA;
                }
                int k0 = akq * 8;
                u.stage.As[k0 + 0][arow] = a0.x; u.stage.As[k0 + 1][arow] = a0.y;
                u.stage.As[k0 + 2][arow] = a0.z; u.stage.As[k0 + 3][arow] = a0.w;
                u.stage.As[k0 + 4][arow] = a1.x; u.stage.As[k0 + 5][arow] = a1.y;
                u.stage.As[k0 + 6][arow] = a1.z; u.stage.As[k0 + 7][arow] = a1.w;
            }
            {
                const float* bp = src + (size_t)(c0 + bcol) * DD + kb + bkh * 16;
                float4 b0 = *(const float4*)bp;
                float4 b1 = *(const float4*)(bp + 4);
                float4 b2 = *(const float4*)(bp + 8);
                float4 b3 = *(const float4*)(bp + 12);
                if (!PRE) {
                    float nB = nrm[c0 + bcol];
                    b0.x /= nB; b0.y /= nB; b0.z /= nB; b0.w /= nB;
                    b1.x /= nB; b1.y /= nB; b1.z /= nB; b1.w /= nB;
                    b2.x /= nB; b2.y /= nB; b2.z /= nB; b2.w /= nB;
                    b3.x /= nB; b3.y /= nB; b3.z /= nB; b3.w /= nB;
                }
                int k0 = bkh * 16;
                u.stage.Bs[k0 +  0][bcol] = b0.x; u.stage.Bs[k0 +  1][bcol] = b0.y;
                u.stage.Bs[k0 +  2][bcol] = b0.z; u.stage.Bs[k0 +  3][bcol] = b0.w;
                u.stage.Bs[k0 +  4][bcol] = b1.x; u.stage.Bs[k0 +  5][bcol] = b1.y;
                u.stage.Bs[k0 +  6][bcol] = b1.z; u.stage.Bs[k0 +  7][bcol] = b1.w;
                u.stage.Bs[k0 +  8][bcol] = b2.x; u.stage.Bs[k0 +  9][bcol] = b2.y;
                u.stage.Bs[k0 + 10][bcol] = b2.z; u.stage.Bs[k0 + 11][bcol] = b2.w;
                u.stage.Bs[k0 + 12][bcol] = b3.x; u.stage.Bs[k0 + 13][bcol] = b3.y;
                u.stage.Bs[k0 + 14][bcol] = b3.z; u.stage.Bs[k0 + 15][bcol] = b3.w;
            }
            __syncthreads();
            #pragma unroll
            for (int kk = 0; kk < KT; kk++) {
                float4 av  = *(const float4*)&u.stage.As[kk][ty * 4];
                float4 bv0 = *(const float4*)&u.stage.Bs[kk][tx * 4];
                float4 bv1 = *(const float4*)&u.stage.Bs[kk][64 + tx * 4];
                float ar[4] = {av.x, av.y, av.z, av.w};
                float br[8] = {bv0.x, bv0.y, bv0.z, bv0.w,
                               bv1.x, bv1.y, bv1.z, bv1.w};
                #pragma unroll
                for (int rr = 0; rr < 4; rr++)
                    #pragma unroll
                    for (int cc = 0; cc < 8; cc++)
                        acc[rr][cc] = __builtin_fmaf(ar[rr], br[cc], acc[rr][cc]);
            }
        }
        __syncthreads();
        {
            #pragma unroll
            for (int rr = 0; rr < 4; rr++) {
                *(float4*)&u.sim[ty * 4 + rr][tx * 4] =
                    make_float4(acc[rr][0], acc[rr][1], acc[rr][2], acc[rr][3]);
                *(float4*)&u.sim[ty * 4 + rr][64 + tx * 4] =
                    make_float4(acc[rr][4], acc[rr][5], acc[rr][6], acc[rr][7]);
            }
        }
        __syncthreads();
        if ((t & 3) == 0) {
            const int lr = t >> 2, grow = r0 + lr;
            float vmin = tval[lr][KNN - 1];
            for (int j = 0; j < CT / 4; j++) {
                float4 v4 = *(const float4*)&u.sim[lr][j * 4];
                float vs[4] = {v4.x, v4.y, v4.z, v4.w};
                #pragma unroll
                for (int e = 0; e < 4; e++) {
                    int cc2 = c0 + j * 4 + e;
                    float v = vs[e];
                    if (cc2 == grow) continue;
                    if (v > vmin) {
                        int p = KNN - 1;
                        while (p > 0 && tval[lr][p - 1] < v) {
                            tval[lr][p] = tval[lr][p - 1];
                            tidx[lr][p] = tidx[lr][p - 1];
                            p--;
                        }
                        tval[lr][p] = v;
                        tidx[lr][p] = cc2;
                        vmin = tval[lr][KNN - 1];
                    }
                }
            }
        }
    }
    __syncthreads();
    for (int i = t; i < MT * KNN; i += 256) {
        int lr = i / KNN, j = i % KNN;
        int grow = r0 + lr;
        out[(size_t)grow * KNN + j]            = grow;
        out[(size_t)NN * KNN + grow * KNN + j] = tidx[lr][j];
    }
}

extern "C" void kernel_launch(void* const* d_in, const int* in_sizes, int n_in,
                              void* d_out, int out_size, void* d_ws, size_t ws_size,
                              hipStream_t stream) {
    const float* feat = (const float*)d_in[0];
    int* out = (int*)d_out;
    char* ws = (char*)d_ws;

    const size_t oNrm  = 0;
    const size_t oFn   = 64 * 1024;
    const size_t oFnb  = oFn  + (size_t)NN * DD * 4;        // +32 MB
    const size_t oLv   = oFnb + (size_t)NN * DD * 2;        // +16 MB
    const size_t oLi   = oLv  + (size_t)NN * CAND * 4;      // +1.5 MB
    const size_t oSim  = oLi  + (size_t)NN * CAND * 4;      // +1.5 MB
    const size_t need  = oSim + (size_t)NN * STRIPW * 2;    // +128 MB
    float*  nrm  = (float*)(ws + oNrm);
    float*  fn   = (float*)(ws + oFn);
    ushort* fnb  = (ushort*)(ws + oFnb);
    float*  lval = (float*)(ws + oLv);
    int*    lidx = (int*)(ws + oLi);
    __half* simS = (__half*)(ws + oSim);

    norm_kernel<<<NN / 64, 256, 0, stream>>>(feat, nrm);

    if (ws_size >= need) {
        fn_kernel<<<(NN * DD / 4) / 256, 256, 0, stream>>>(feat, nrm, fn, fnb);
        for (int s = 0; s < NSTRIP; s++) {
            dim3 ggrid(STRIPW / 128, NN / 128);
            gemm_kernel<<<ggrid, 256, 0, stream>>>(fnb, s * STRIPW, simS);
            select_kernel<<<NN / 4, 256, 0, stream>>>((const __half2*)simS,
                                                      s * STRIPW, s == 0,
                                                      lval, lidx);
        }
        rescore_kernel<<<NN / 8, 256, 0, stream>>>(fn, lidx, out);
    } else if (ws_size >= oFn + (size_t)NN * DD * 4) {
        fn_kernel<<<(NN * DD / 4) / 256, 256, 0, stream>>>(feat, nrm, fn,
                                                           (ushort*)(ws + oFn));
        knn_exact_kernel<true><<<NN / MT, 256, 0, stream>>>(fn, nrm, out);
    } else {
        knn_exact_kernel<false><<<NN / MT, 256, 0, stream>>>(feat, nrm, out);
    }
}